// Round 16
// baseline (339.712 us; speedup 1.0000x reference)
//
#include <hip/hip_runtime.h>

#define DIM 128
#define ALPHA 0.1f
#define BETA 0.40546510810816438f  // log(0.5/1 + 1.0)

typedef __attribute__((ext_vector_type(8))) short short8v;  // 8 bf16 (4 VGPRs)
typedef __attribute__((ext_vector_type(4))) float float4v;  // MFMA acc

static __device__ inline unsigned short f2bf(float f) {
  union { float f; unsigned u; } a;
  a.f = f;
  unsigned r = a.u + 0x7fff + ((a.u >> 16) & 1);  // round-to-nearest-even
  return (unsigned short)(r >> 16);
}

// ---------------- fused prep: count+rank | convert_x | convert_w ----------------
__global__ __launch_bounds__(256) void prep(const int* __restrict__ col,
                                            int* __restrict__ counts,
                                            int* __restrict__ rank,
                                            const float* __restrict__ x,
                                            short* __restrict__ xb,
                                            const float* __restrict__ W,
                                            short* __restrict__ Wb,
                                            int E, int total4, int cntBlocks,
                                            int cvtXBlocks) {
  int b = blockIdx.x;
  if (b < cntBlocks) {
    int e = b * 256 + threadIdx.x;
    if (e < E) rank[e] = atomicAdd(&counts[col[e]], 1);
  } else if (b < cntBlocks + cvtXBlocks) {
    int i = (b - cntBlocks) * 256 + threadIdx.x;
    if (i < total4) {
      float4 v = ((const float4*)x)[i];
      ((short4*)xb)[i] = make_short4((short)f2bf(v.x), (short)f2bf(v.y),
                                     (short)f2bf(v.z), (short)f2bf(v.w));
    }
  } else {
    int i = (b - cntBlocks - cvtXBlocks) * 256 + threadIdx.x;
    if (i < 128 * 32) {
      float4 v = ((const float4*)W)[i];
      ((short4*)Wb)[i] = make_short4((short)f2bf(v.x), (short)f2bf(v.y),
                                     (short)f2bf(v.z), (short)f2bf(v.w));
    }
  }
}

// ---------------- single-kernel scan: per-block LDS scan + domino lookback --------
// flags[] zeroed by the caller's memset each launch. All blocks co-resident
// (196 blocks <= 256 CUs) so the serial chain cannot deadlock. Deterministic.
__global__ __launch_bounds__(256) void scan_fused(const int* __restrict__ counts,
                                                  int* __restrict__ offsets,
                                                  int* __restrict__ flags,
                                                  int* __restrict__ totals,
                                                  int N, int E) {
  __shared__ int sm[256];
  __shared__ int smP;
  const int tid = threadIdx.x;
  const int b = blockIdx.x;
  const int gid = b * 256 + tid;
  int v = (gid < N) ? counts[gid] : 0;
  sm[tid] = v;
  __syncthreads();
  for (int off = 1; off < 256; off <<= 1) {
    int t = (tid >= off) ? sm[tid - off] : 0;
    __syncthreads();
    sm[tid] += t;
    __syncthreads();
  }
  int incl = sm[tid];
  int T = sm[255];
  if (tid == 0) {
    int P = 0;
    if (b > 0) {
      while (atomicAdd(&flags[b - 1], 0) == 0) {}
      P = atomicAdd(&totals[b - 1], 0);
    }
    smP = P;
    atomicExch(&totals[b], P + T);
    __threadfence();
    atomicExch(&flags[b], 1);
  }
  __syncthreads();
  int P = smP;
  if (gid < N) offsets[gid] = P + incl - v;
  else if (gid == N) offsets[N] = E;
}

// atomic-free fill: slot = offsets[col] + rank (precomputed in prep)
__global__ __launch_bounds__(256) void fill_edges(const int* __restrict__ row,
                                                  const int* __restrict__ col,
                                                  const float* __restrict__ nrm,
                                                  const int* __restrict__ offsets,
                                                  const int* __restrict__ rank,
                                                  int2* __restrict__ emeta, int E) {
  int e = blockIdx.x * 256 + threadIdx.x;
  if (e >= E) return;
  int c = col[e];
  int idx = offsets[c] + rank[e];
  float s = (1.0f - ALPHA) * nrm[e];
  emeta[idx] = make_int2(row[e], __float_as_int(s));
}

// ---------------- fused gather + GEMM ----------------
// Phase 1: proven shfl inner loop (R15, 49us) + NEW: software-pipelined first-batch
// meta loads across the 4-node q loop (prefetch node q+1's emeta while node q
// computes). Summation order identical to R15.
// Phase 2: 16x128 @ 128x128^T bf16 MFMA from LDS tile + L2-resident global Wb.
__global__ __launch_bounds__(256) void gather_gemm(const unsigned* __restrict__ xb,
                                                   const float* __restrict__ x0,
                                                   const int* __restrict__ offs,
                                                   const int2* __restrict__ emeta,
                                                   const short* __restrict__ Wb,
                                                   float* __restrict__ out, int N) {
  __shared__ unsigned short hb[16][136];
  const int tid = threadIdx.x;
  const int lane = tid & 63;
  const int wave = tid >> 6;
  const int row0 = blockIdx.x * 16;

  // node range bounds for this wave's 4 nodes (5 loads; offs[N]=E pads OOB nodes)
  const int basen = row0 + wave * 4;
  int o[5];
#pragma unroll
  for (int k = 0; k < 5; ++k) {
    int nn = basen + k;
    o[k] = offs[nn <= N ? nn : N];
  }

  // prefetch first-batch meta for node 0
  int2 mcur = make_int2(0, 0);
  if (o[0] + lane < o[1]) mcur = emeta[o[0] + lane];

#pragma unroll
  for (int q = 0; q < 4; ++q) {
    const int ss = o[q], tt = o[q + 1];
    // prefetch next node's first batch while this node computes
    int2 mnext = make_int2(0, 0);
    if (q < 3 && o[q + 1] + lane < o[q + 2]) mnext = emeta[o[q + 1] + lane];

    const int lr = wave * 4 + q;
    const int n = row0 + lr;
    unsigned packed = 0;
    if (n < N) {
      float2 v0 = *(const float2*)(x0 + (size_t)n * DIM + 2 * lane);
      float accx[8], accy[8];
#pragma unroll
      for (int j = 0; j < 8; ++j) { accx[j] = 0.0f; accy[j] = 0.0f; }

      // batch 0 from prefetched meta
      {
        int r = mcur.x;
        float sc = __int_as_float(mcur.y);
        int cnt = tt - ss;
        if (cnt > 64) cnt = 64;
        if (cnt < 0) cnt = 0;
        int cnt8 = (cnt + 7) & ~7;
        for (int i = 0; i < cnt8; i += 8) {
#pragma unroll
          for (int j = 0; j < 8; ++j) {
            int rj = __shfl(r, i + j);
            float sj = __shfl(sc, i + j);
            unsigned u = xb[(size_t)rj * (DIM / 2) + lane];
            accx[j] += sj * __uint_as_float(u << 16);
            accy[j] += sj * __uint_as_float(u & 0xffff0000u);
          }
        }
      }
      // batches 1+ (deg > 64, rare): load inline as before
      for (int base = ss + 64; base < tt; base += 64) {
        int r = 0;
        float sc = 0.0f;
        if (base + lane < tt) {
          int2 m = emeta[base + lane];
          r = m.x;
          sc = __int_as_float(m.y);
        }
        int cnt = tt - base;
        if (cnt > 64) cnt = 64;
        int cnt8 = (cnt + 7) & ~7;
        for (int i = 0; i < cnt8; i += 8) {
#pragma unroll
          for (int j = 0; j < 8; ++j) {
            int rj = __shfl(r, i + j);
            float sj = __shfl(sc, i + j);
            unsigned u = xb[(size_t)rj * (DIM / 2) + lane];
            accx[j] += sj * __uint_as_float(u << 16);
            accy[j] += sj * __uint_as_float(u & 0xffff0000u);
          }
        }
      }
      float sx = ((accx[0] + accx[1]) + (accx[2] + accx[3])) +
                 ((accx[4] + accx[5]) + (accx[6] + accx[7]));
      float sy = ((accy[0] + accy[1]) + (accy[2] + accy[3])) +
                 ((accy[4] + accy[5]) + (accy[6] + accy[7]));
      float hx = sx + ALPHA * v0.x;
      float hy = sy + ALPHA * v0.y;
      packed = (unsigned)f2bf(hx) | ((unsigned)f2bf(hy) << 16);
    }
    *(unsigned*)&hb[lr][2 * lane] = packed;
    mcur = mnext;
  }
  __syncthreads();

  const int arow = lane & 15;
  const int kg = (lane >> 4) * 8;
  short8v a[4];
#pragma unroll
  for (int s = 0; s < 4; ++s) a[s] = *(const short8v*)&hb[arow][s * 32 + kg];

#pragma unroll
  for (int j2 = 0; j2 < 2; ++j2) {
    const int jt = wave * 2 + j2;
    const int bcol = jt * 16 + (lane & 15);
    float4v acc = {0.0f, 0.0f, 0.0f, 0.0f};
#pragma unroll
    for (int s = 0; s < 4; ++s) {
      short8v b = *(const short8v*)(Wb + (size_t)bcol * DIM + s * 32 + kg);
      acc = __builtin_amdgcn_mfma_f32_16x16x32_bf16(a[s], b, acc, 0, 0, 0);
    }
    const int lr0 = (lane >> 4) << 2;
#pragma unroll
    for (int p = 0; p < 4; ++p) {
      int R = row0 + lr0 + p;
      if (R < N) {
        int c = jt * 16 + (lane & 15);
        float hv = __uint_as_float(((unsigned)hb[lr0 + p][c]) << 16);
        out[(size_t)R * DIM + c] = (1.0f - BETA) * hv + BETA * acc[p];
      }
    }
  }
}

// ---------------- mid-tier: count+rank, f32 gather + LDS-staged MFMA ----------------
__global__ __launch_bounds__(256) void count_edges(const int* __restrict__ col,
                                                   int* __restrict__ counts,
                                                   int* __restrict__ rank, int E) {
  int e = blockIdx.x * 256 + threadIdx.x;
  if (e < E) rank[e] = atomicAdd(&counts[col[e]], 1);
}

__global__ __launch_bounds__(256) void gather_nodes_f32(const float* __restrict__ x,
                                                        const float* __restrict__ x0,
                                                        const int* __restrict__ offs,
                                                        const int2* __restrict__ emeta,
                                                        float* __restrict__ h, int N) {
  int lane = threadIdx.x & 63;
  int gwave = blockIdx.x * 4 + (threadIdx.x >> 6);
  int nwaves = gridDim.x * 4;
  int dbase = 2 * lane;
  for (int n = gwave; n < N; n += nwaves) {
    int s = offs[n], t = offs[n + 1];
    float ax = 0, ay = 0, bx = 0, by = 0;
    for (int base = s; base < t; base += 64) {
      int r = 0;
      float sc = 0.0f;
      if (base + lane < t) {
        int2 m = emeta[base + lane];
        r = m.x;
        sc = __int_as_float(m.y);
      }
      int cnt = t - base;
      if (cnt > 64) cnt = 64;
      int cnt4 = (cnt + 3) & ~3;
      for (int i = 0; i < cnt4; i += 4) {
        int r0 = __shfl(r, i), r1 = __shfl(r, i + 1);
        int r2 = __shfl(r, i + 2), r3 = __shfl(r, i + 3);
        float s0 = __shfl(sc, i), s1 = __shfl(sc, i + 1);
        float s2 = __shfl(sc, i + 2), s3 = __shfl(sc, i + 3);
        float2 v0 = *(const float2*)(x + (size_t)r0 * DIM + dbase);
        float2 v1 = *(const float2*)(x + (size_t)r1 * DIM + dbase);
        float2 v2 = *(const float2*)(x + (size_t)r2 * DIM + dbase);
        float2 v3 = *(const float2*)(x + (size_t)r3 * DIM + dbase);
        ax += s0 * v0.x; ay += s0 * v0.y;
        bx += s1 * v1.x; by += s1 * v1.y;
        ax += s2 * v2.x; ay += s2 * v2.y;
        bx += s3 * v3.x; by += s3 * v3.y;
      }
    }
    float2 v0 = *(const float2*)(x0 + (size_t)n * DIM + dbase);
    float2 hv;
    hv.x = (ax + bx) + ALPHA * v0.x;
    hv.y = (ay + by) + ALPHA * v0.y;
    *(float2*)(h + (size_t)n * DIM + dbase) = hv;
  }
}

__global__ __launch_bounds__(256) void final_mfma(const float* __restrict__ W,
                                                  float* __restrict__ out, int N) {
  __shared__ short W_s[128][136];
  __shared__ short h_s[64][136];
  const int tid = threadIdx.x;
  const int lane = tid & 63;
  const int wave = tid >> 6;
  const int row0 = blockIdx.x * 64;

  for (int idx = tid; idx < 128 * 32; idx += 256) {
    int r = idx >> 5, c4 = idx & 31;
    float4 v = ((const float4*)(W + (size_t)r * DIM))[c4];
    *(short4*)&W_s[r][c4 * 4] = make_short4((short)f2bf(v.x), (short)f2bf(v.y),
                                            (short)f2bf(v.z), (short)f2bf(v.w));
  }
  for (int idx = tid; idx < 64 * 32; idx += 256) {
    int r = idx >> 5, c4 = idx & 31;
    int R = row0 + r;
    short4 sv = make_short4(0, 0, 0, 0);
    if (R < N) {
      float4 v = ((const float4*)(out + (size_t)R * DIM))[c4];
      sv = make_short4((short)f2bf(v.x), (short)f2bf(v.y), (short)f2bf(v.z),
                       (short)f2bf(v.w));
    }
    *(short4*)&h_s[r][c4 * 4] = sv;
  }
  __syncthreads();

  const int wr0 = wave * 16;
  const int arow = wr0 + (lane & 15);
  const int kg = (lane >> 4) * 8;
  short8v a[4];
#pragma unroll
  for (int s = 0; s < 4; ++s) a[s] = *(const short8v*)&h_s[arow][s * 32 + kg];

#pragma unroll
  for (int jt = 0; jt < 8; ++jt) {
    const int bcol = jt * 16 + (lane & 15);
    float4v acc = {0.0f, 0.0f, 0.0f, 0.0f};
#pragma unroll
    for (int s = 0; s < 4; ++s) {
      short8v b = *(const short8v*)&W_s[bcol][s * 32 + kg];
      acc = __builtin_amdgcn_mfma_f32_16x16x32_bf16(a[s], b, acc, 0, 0, 0);
    }
    const int rbase = row0 + wr0 + ((lane >> 4) << 2);
#pragma unroll
    for (int p = 0; p < 4; ++p) {
      int R = rbase + p;
      if (R < N) {
        size_t off = (size_t)R * DIM + jt * 16 + (lane & 15);
        out[off] = (1.0f - BETA) * out[off] + BETA * acc[p];
      }
    }
  }
}

// ---------------- last-resort atomic fallback ----------------
__global__ __launch_bounds__(256) void init_h(const float* __restrict__ x0,
                                              float* __restrict__ h, int total4) {
  int i = blockIdx.x * 256 + threadIdx.x;
  if (i < total4) {
    float4 v = ((const float4*)x0)[i];
    v.x *= ALPHA; v.y *= ALPHA; v.z *= ALPHA; v.w *= ALPHA;
    ((float4*)h)[i] = v;
  }
}

__global__ __launch_bounds__(256) void scatter_edges(const float* __restrict__ x,
                                                     const int* __restrict__ row,
                                                     const int* __restrict__ col,
                                                     const float* __restrict__ nrm,
                                                     float* __restrict__ h, int E) {
  int gid = blockIdx.x * 256 + threadIdx.x;
  int e = gid >> 5;
  if (e >= E) return;
  int d4 = (gid & 31) << 2;
  int r = row[e];
  int c = col[e];
  float s = (1.0f - ALPHA) * nrm[e];
  const float4 v = *(const float4*)(x + (size_t)r * DIM + d4);
  float* dst = h + (size_t)c * DIM + d4;
  atomicAdd(dst + 0, s * v.x);
  atomicAdd(dst + 1, s * v.y);
  atomicAdd(dst + 2, s * v.z);
  atomicAdd(dst + 3, s * v.w);
}

extern "C" void kernel_launch(void* const* d_in, const int* in_sizes, int n_in,
                              void* d_out, int out_size, void* d_ws, size_t ws_size,
                              hipStream_t stream) {
  const float* x = (const float*)d_in[0];
  const float* x0 = (const float*)d_in[1];
  const int* ei = (const int*)d_in[2];
  const float* nrm = (const float*)d_in[3];
  const float* W = (const float*)d_in[4];
  float* out = (float*)d_out;

  const int N = in_sizes[0] / DIM;
  const int E = in_sizes[2] / 2;
  const int* row = ei;
  const int* col = ei + E;

  // ws: counts[N+1] | flags[256] | offsets[N+1] | totals[256] | rank[E]
  //     | emeta int2[E] | xb bf16[N*DIM] | Wb bf16[128*128]
  const size_t csrNeed =
      (size_t)(2 * (N + 1) + 512 + E) * sizeof(int) + (size_t)E * 8;
  const size_t fullNeed =
      csrNeed + (size_t)N * DIM * sizeof(short) + 128 * 128 * sizeof(short);

  const int eBlocks = (E + 255) / 256;
  const int nBlocks = (N + 255) / 256;  // scan blocks (domino works for any count)

  if (ws_size >= csrNeed && nBlocks <= 256) {
    int* counts = (int*)d_ws;
    int* flags = counts + (N + 1);
    int* offsets = flags + 256;
    int* totals = offsets + (N + 1);
    int* rank = totals + 256;
    int2* emeta = (int2*)(rank + E);
    short* xb = (short*)(emeta + E);
    short* Wb = xb + (size_t)N * DIM;

    // zero counts AND flags in one memset (contiguous)
    hipMemsetAsync(counts, 0, (size_t)(N + 1 + 256) * sizeof(int), stream);

    if (ws_size >= fullNeed) {
      const int total4 = N * DIM / 4;
      const int cvtXBlocks = (total4 + 255) / 256;
      const int prepBlocks = eBlocks + cvtXBlocks + 16;
      hipLaunchKernelGGL(prep, dim3(prepBlocks), dim3(256), 0, stream, col, counts, rank, x, xb,
                         W, Wb, E, total4, eBlocks, cvtXBlocks);
      hipLaunchKernelGGL(scan_fused, dim3(nBlocks), dim3(256), 0, stream, counts, offsets, flags,
                         totals, N, E);
      hipLaunchKernelGGL(fill_edges, dim3(eBlocks), dim3(256), 0, stream, row, col, nrm, offsets,
                         rank, emeta, E);
      const int t16 = (N + 15) / 16;
      hipLaunchKernelGGL(gather_gemm, dim3(t16), dim3(256), 0, stream, (const unsigned*)xb, x0,
                         offsets, emeta, Wb, out, N);
    } else {
      hipLaunchKernelGGL(count_edges, dim3(eBlocks), dim3(256), 0, stream, col, counts, rank, E);
      hipLaunchKernelGGL(scan_fused, dim3(nBlocks), dim3(256), 0, stream, counts, offsets, flags,
                         totals, N, E);
      hipLaunchKernelGGL(fill_edges, dim3(eBlocks), dim3(256), 0, stream, row, col, nrm, offsets,
                         rank, emeta, E);
      const int gBlocks = (N + 3) / 4;
      hipLaunchKernelGGL(gather_nodes_f32, dim3(gBlocks), dim3(256), 0, stream, x, x0, offsets,
                         emeta, out, N);
      hipLaunchKernelGGL(final_mfma, dim3((N + 63) / 64), dim3(256), 0, stream, W, out, N);
    }
  } else {
    int total4 = N * DIM / 4;
    hipLaunchKernelGGL(init_h, dim3((total4 + 255) / 256), dim3(256), 0, stream, x0, out, total4);
    long long threads = (long long)E * 32;
    hipLaunchKernelGGL(scatter_edges, dim3((int)((threads + 255) / 256)), dim3(256), 0, stream, x,
                       row, col, nrm, out, E);
    hipLaunchKernelGGL(final_mfma, dim3((N + 63) / 64), dim3(256), 0, stream, W, out, N);
  }
}

// Round 18
// 102.722 us; speedup vs baseline: 3.3071x; 3.3071x over previous
//
#include <hip/hip_runtime.h>

#define DIM 128
#define ALPHA 0.1f
#define BETA 0.40546510810816438f  // log(0.5/1 + 1.0)

typedef __attribute__((ext_vector_type(8))) short short8v;  // 8 bf16 (4 VGPRs)
typedef __attribute__((ext_vector_type(4))) float float4v;  // MFMA acc

static __device__ inline unsigned short f2bf(float f) {
  union { float f; unsigned u; } a;
  a.f = f;
  unsigned r = a.u + 0x7fff + ((a.u >> 16) & 1);  // round-to-nearest-even
  return (unsigned short)(r >> 16);
}

// ---------------- fused prep: count+rank | convert_x | convert_w ----------------
__global__ __launch_bounds__(256) void prep(const int* __restrict__ col,
                                            int* __restrict__ counts,
                                            int* __restrict__ rank,
                                            const float* __restrict__ x,
                                            short* __restrict__ xb,
                                            const float* __restrict__ W,
                                            short* __restrict__ Wb,
                                            int E, int total4, int cntBlocks,
                                            int cvtXBlocks) {
  int b = blockIdx.x;
  if (b < cntBlocks) {
    int e = b * 256 + threadIdx.x;
    if (e < E) rank[e] = atomicAdd(&counts[col[e]], 1);
  } else if (b < cntBlocks + cvtXBlocks) {
    int i = (b - cntBlocks) * 256 + threadIdx.x;
    if (i < total4) {
      float4 v = ((const float4*)x)[i];
      ((short4*)xb)[i] = make_short4((short)f2bf(v.x), (short)f2bf(v.y),
                                     (short)f2bf(v.z), (short)f2bf(v.w));
    }
  } else {
    int i = (b - cntBlocks - cvtXBlocks) * 256 + threadIdx.x;
    if (i < 128 * 32) {
      float4 v = ((const float4*)W)[i];
      ((short4*)Wb)[i] = make_short4((short)f2bf(v.x), (short)f2bf(v.y),
                                     (short)f2bf(v.z), (short)f2bf(v.w));
    }
  }
}

// per-block exclusive scan of counts -> offsets (local), block totals -> blockSums
// (R16 lesson: domino/lookback scan costs ~1.25us per cross-block hop on MI355X —
//  the dumb 2-kernel rescan at ~3us total is the right choice here.)
__global__ __launch_bounds__(256) void scan_blocks(const int* __restrict__ counts,
                                                   int* __restrict__ offsets,
                                                   int* __restrict__ blockSums, int N) {
  __shared__ int sm[256];
  int tid = threadIdx.x;
  int gid = blockIdx.x * 256 + tid;
  int v = (gid < N) ? counts[gid] : 0;
  sm[tid] = v;
  __syncthreads();
  for (int off = 1; off < 256; off <<= 1) {
    int t = (tid >= off) ? sm[tid - off] : 0;
    __syncthreads();
    sm[tid] += t;
    __syncthreads();
  }
  if (gid < N) offsets[gid] = sm[tid] - v;
  if (tid == 255) blockSums[blockIdx.x] = sm[255];
}

// each block redundantly scans blockSums (nb<=256) in LDS, adds its prefix,
// sets offsets[N]=E.
__global__ __launch_bounds__(256) void scan_off(int* __restrict__ offsets,
                                                const int* __restrict__ blockSums,
                                                int N, int E, int nb) {
  __shared__ int sm[256];
  int tid = threadIdx.x;
  int v = (tid < nb) ? blockSums[tid] : 0;
  sm[tid] = v;
  __syncthreads();
  for (int off = 1; off < 256; off <<= 1) {
    int t = (tid >= off) ? sm[tid - off] : 0;
    __syncthreads();
    sm[tid] += t;
    __syncthreads();
  }
  int excl = sm[tid] - v;
  __syncthreads();
  sm[tid] = excl;
  __syncthreads();
  int pref = sm[blockIdx.x];

  int gid = blockIdx.x * 256 + tid;
  if (gid < N) offsets[gid] += pref;
  else if (gid == N) offsets[N] = E;
}

// atomic-free fill: slot = offsets[col] + rank (precomputed in prep)
__global__ __launch_bounds__(256) void fill_edges(const int* __restrict__ row,
                                                  const int* __restrict__ col,
                                                  const float* __restrict__ nrm,
                                                  const int* __restrict__ offsets,
                                                  const int* __restrict__ rank,
                                                  int2* __restrict__ emeta, int E) {
  int e = blockIdx.x * 256 + threadIdx.x;
  if (e >= E) return;
  int c = col[e];
  int idx = offsets[c] + rank[e];
  float s = (1.0f - ALPHA) * nrm[e];
  emeta[idx] = make_int2(row[e], __float_as_int(s));
}

// ---------------- fused gather + GEMM ----------------
// Phase 1: proven shfl inner loop + software-pipelined first-batch meta prefetch
// across the 4-node q loop (R16: ~5us win). Summation order identical to R15.
// Phase 2: 16x128 @ 128x128^T bf16 MFMA from LDS tile + L2-resident global Wb.
__global__ __launch_bounds__(256) void gather_gemm(const unsigned* __restrict__ xb,
                                                   const float* __restrict__ x0,
                                                   const int* __restrict__ offs,
                                                   const int2* __restrict__ emeta,
                                                   const short* __restrict__ Wb,
                                                   float* __restrict__ out, int N) {
  __shared__ unsigned short hb[16][136];
  const int tid = threadIdx.x;
  const int lane = tid & 63;
  const int wave = tid >> 6;
  const int row0 = blockIdx.x * 16;

  // node range bounds for this wave's 4 nodes (5 loads; offs[N]=E pads OOB nodes)
  const int basen = row0 + wave * 4;
  int o[5];
#pragma unroll
  for (int k = 0; k < 5; ++k) {
    int nn = basen + k;
    o[k] = offs[nn <= N ? nn : N];
  }

  // prefetch first-batch meta for node 0
  int2 mcur = make_int2(0, 0);
  if (o[0] + lane < o[1]) mcur = emeta[o[0] + lane];

#pragma unroll
  for (int q = 0; q < 4; ++q) {
    const int ss = o[q], tt = o[q + 1];
    // prefetch next node's first batch while this node computes
    int2 mnext = make_int2(0, 0);
    if (q < 3 && o[q + 1] + lane < o[q + 2]) mnext = emeta[o[q + 1] + lane];

    const int lr = wave * 4 + q;
    const int n = row0 + lr;
    unsigned packed = 0;
    if (n < N) {
      float2 v0 = *(const float2*)(x0 + (size_t)n * DIM + 2 * lane);
      float accx[8], accy[8];
#pragma unroll
      for (int j = 0; j < 8; ++j) { accx[j] = 0.0f; accy[j] = 0.0f; }

      // batch 0 from prefetched meta
      {
        int r = mcur.x;
        float sc = __int_as_float(mcur.y);
        int cnt = tt - ss;
        if (cnt > 64) cnt = 64;
        if (cnt < 0) cnt = 0;
        int cnt8 = (cnt + 7) & ~7;
        for (int i = 0; i < cnt8; i += 8) {
#pragma unroll
          for (int j = 0; j < 8; ++j) {
            int rj = __shfl(r, i + j);
            float sj = __shfl(sc, i + j);
            unsigned u = xb[(size_t)rj * (DIM / 2) + lane];
            accx[j] += sj * __uint_as_float(u << 16);
            accy[j] += sj * __uint_as_float(u & 0xffff0000u);
          }
        }
      }
      // batches 1+ (deg > 64, rare): load inline
      for (int base = ss + 64; base < tt; base += 64) {
        int r = 0;
        float sc = 0.0f;
        if (base + lane < tt) {
          int2 m = emeta[base + lane];
          r = m.x;
          sc = __int_as_float(m.y);
        }
        int cnt = tt - base;
        if (cnt > 64) cnt = 64;
        int cnt8 = (cnt + 7) & ~7;
        for (int i = 0; i < cnt8; i += 8) {
#pragma unroll
          for (int j = 0; j < 8; ++j) {
            int rj = __shfl(r, i + j);
            float sj = __shfl(sc, i + j);
            unsigned u = xb[(size_t)rj * (DIM / 2) + lane];
            accx[j] += sj * __uint_as_float(u << 16);
            accy[j] += sj * __uint_as_float(u & 0xffff0000u);
          }
        }
      }
      float sx = ((accx[0] + accx[1]) + (accx[2] + accx[3])) +
                 ((accx[4] + accx[5]) + (accx[6] + accx[7]));
      float sy = ((accy[0] + accy[1]) + (accy[2] + accy[3])) +
                 ((accy[4] + accy[5]) + (accy[6] + accy[7]));
      float hx = sx + ALPHA * v0.x;
      float hy = sy + ALPHA * v0.y;
      packed = (unsigned)f2bf(hx) | ((unsigned)f2bf(hy) << 16);
    }
    *(unsigned*)&hb[lr][2 * lane] = packed;
    mcur = mnext;
  }
  __syncthreads();

  const int arow = lane & 15;
  const int kg = (lane >> 4) * 8;
  short8v a[4];
#pragma unroll
  for (int s = 0; s < 4; ++s) a[s] = *(const short8v*)&hb[arow][s * 32 + kg];

#pragma unroll
  for (int j2 = 0; j2 < 2; ++j2) {
    const int jt = wave * 2 + j2;
    const int bcol = jt * 16 + (lane & 15);
    float4v acc = {0.0f, 0.0f, 0.0f, 0.0f};
#pragma unroll
    for (int s = 0; s < 4; ++s) {
      short8v b = *(const short8v*)(Wb + (size_t)bcol * DIM + s * 32 + kg);
      acc = __builtin_amdgcn_mfma_f32_16x16x32_bf16(a[s], b, acc, 0, 0, 0);
    }
    const int lr0 = (lane >> 4) << 2;
#pragma unroll
    for (int p = 0; p < 4; ++p) {
      int R = row0 + lr0 + p;
      if (R < N) {
        int c = jt * 16 + (lane & 15);
        float hv = __uint_as_float(((unsigned)hb[lr0 + p][c]) << 16);
        out[(size_t)R * DIM + c] = (1.0f - BETA) * hv + BETA * acc[p];
      }
    }
  }
}

// ---------------- mid-tier: count+rank, f32 gather + LDS-staged MFMA ----------------
__global__ __launch_bounds__(256) void count_edges(const int* __restrict__ col,
                                                   int* __restrict__ counts,
                                                   int* __restrict__ rank, int E) {
  int e = blockIdx.x * 256 + threadIdx.x;
  if (e < E) rank[e] = atomicAdd(&counts[col[e]], 1);
}

__global__ __launch_bounds__(256) void gather_nodes_f32(const float* __restrict__ x,
                                                        const float* __restrict__ x0,
                                                        const int* __restrict__ offs,
                                                        const int2* __restrict__ emeta,
                                                        float* __restrict__ h, int N) {
  int lane = threadIdx.x & 63;
  int gwave = blockIdx.x * 4 + (threadIdx.x >> 6);
  int nwaves = gridDim.x * 4;
  int dbase = 2 * lane;
  for (int n = gwave; n < N; n += nwaves) {
    int s = offs[n], t = offs[n + 1];
    float ax = 0, ay = 0, bx = 0, by = 0;
    for (int base = s; base < t; base += 64) {
      int r = 0;
      float sc = 0.0f;
      if (base + lane < t) {
        int2 m = emeta[base + lane];
        r = m.x;
        sc = __int_as_float(m.y);
      }
      int cnt = t - base;
      if (cnt > 64) cnt = 64;
      int cnt4 = (cnt + 3) & ~3;
      for (int i = 0; i < cnt4; i += 4) {
        int r0 = __shfl(r, i), r1 = __shfl(r, i + 1);
        int r2 = __shfl(r, i + 2), r3 = __shfl(r, i + 3);
        float s0 = __shfl(sc, i), s1 = __shfl(sc, i + 1);
        float s2 = __shfl(sc, i + 2), s3 = __shfl(sc, i + 3);
        float2 v0 = *(const float2*)(x + (size_t)r0 * DIM + dbase);
        float2 v1 = *(const float2*)(x + (size_t)r1 * DIM + dbase);
        float2 v2 = *(const float2*)(x + (size_t)r2 * DIM + dbase);
        float2 v3 = *(const float2*)(x + (size_t)r3 * DIM + dbase);
        ax += s0 * v0.x; ay += s0 * v0.y;
        bx += s1 * v1.x; by += s1 * v1.y;
        ax += s2 * v2.x; ay += s2 * v2.y;
        bx += s3 * v3.x; by += s3 * v3.y;
      }
    }
    float2 v0 = *(const float2*)(x0 + (size_t)n * DIM + dbase);
    float2 hv;
    hv.x = (ax + bx) + ALPHA * v0.x;
    hv.y = (ay + by) + ALPHA * v0.y;
    *(float2*)(h + (size_t)n * DIM + dbase) = hv;
  }
}

__global__ __launch_bounds__(256) void final_mfma(const float* __restrict__ W,
                                                  float* __restrict__ out, int N) {
  __shared__ short W_s[128][136];
  __shared__ short h_s[64][136];
  const int tid = threadIdx.x;
  const int lane = tid & 63;
  const int wave = tid >> 6;
  const int row0 = blockIdx.x * 64;

  for (int idx = tid; idx < 128 * 32; idx += 256) {
    int r = idx >> 5, c4 = idx & 31;
    float4 v = ((const float4*)(W + (size_t)r * DIM))[c4];
    *(short4*)&W_s[r][c4 * 4] = make_short4((short)f2bf(v.x), (short)f2bf(v.y),
                                            (short)f2bf(v.z), (short)f2bf(v.w));
  }
  for (int idx = tid; idx < 64 * 32; idx += 256) {
    int r = idx >> 5, c4 = idx & 31;
    int R = row0 + r;
    short4 sv = make_short4(0, 0, 0, 0);
    if (R < N) {
      float4 v = ((const float4*)(out + (size_t)R * DIM))[c4];
      sv = make_short4((short)f2bf(v.x), (short)f2bf(v.y), (short)f2bf(v.z),
                       (short)f2bf(v.w));
    }
    *(short4*)&h_s[r][c4 * 4] = sv;
  }
  __syncthreads();

  const int wr0 = wave * 16;
  const int arow = wr0 + (lane & 15);
  const int kg = (lane >> 4) * 8;
  short8v a[4];
#pragma unroll
  for (int s = 0; s < 4; ++s) a[s] = *(const short8v*)&h_s[arow][s * 32 + kg];

#pragma unroll
  for (int jt = 0; jt < 8; ++jt) {
    const int bcol = jt * 16 + (lane & 15);
    float4v acc = {0.0f, 0.0f, 0.0f, 0.0f};
#pragma unroll
    for (int s = 0; s < 4; ++s) {
      short8v b = *(const short8v*)&W_s[bcol][s * 32 + kg];
      acc = __builtin_amdgcn_mfma_f32_16x16x32_bf16(a[s], b, acc, 0, 0, 0);
    }
    const int rbase = row0 + wr0 + ((lane >> 4) << 2);
#pragma unroll
    for (int p = 0; p < 4; ++p) {
      int R = rbase + p;
      if (R < N) {
        size_t off = (size_t)R * DIM + jt * 16 + (lane & 15);
        out[off] = (1.0f - BETA) * out[off] + BETA * acc[p];
      }
    }
  }
}

// ---------------- last-resort atomic fallback ----------------
__global__ __launch_bounds__(256) void init_h(const float* __restrict__ x0,
                                              float* __restrict__ h, int total4) {
  int i = blockIdx.x * 256 + threadIdx.x;
  if (i < total4) {
    float4 v = ((const float4*)x0)[i];
    v.x *= ALPHA; v.y *= ALPHA; v.z *= ALPHA; v.w *= ALPHA;
    ((float4*)h)[i] = v;
  }
}

__global__ __launch_bounds__(256) void scatter_edges(const float* __restrict__ x,
                                                     const int* __restrict__ row,
                                                     const int* __restrict__ col,
                                                     const float* __restrict__ nrm,
                                                     float* __restrict__ h, int E) {
  int gid = blockIdx.x * 256 + threadIdx.x;
  int e = gid >> 5;
  if (e >= E) return;
  int d4 = (gid & 31) << 2;
  int r = row[e];
  int c = col[e];
  float s = (1.0f - ALPHA) * nrm[e];
  const float4 v = *(const float4*)(x + (size_t)r * DIM + d4);
  float* dst = h + (size_t)c * DIM + d4;
  atomicAdd(dst + 0, s * v.x);
  atomicAdd(dst + 1, s * v.y);
  atomicAdd(dst + 2, s * v.z);
  atomicAdd(dst + 3, s * v.w);
}

extern "C" void kernel_launch(void* const* d_in, const int* in_sizes, int n_in,
                              void* d_out, int out_size, void* d_ws, size_t ws_size,
                              hipStream_t stream) {
  const float* x = (const float*)d_in[0];
  const float* x0 = (const float*)d_in[1];
  const int* ei = (const int*)d_in[2];
  const float* nrm = (const float*)d_in[3];
  const float* W = (const float*)d_in[4];
  float* out = (float*)d_out;

  const int N = in_sizes[0] / DIM;
  const int E = in_sizes[2] / 2;
  const int* row = ei;
  const int* col = ei + E;

  // ws: counts[N+1] | offsets[N+1] | blockSums[256] | rank[E] | emeta int2[E]
  //     | xb bf16[N*DIM] | Wb bf16[128*128]
  const size_t csrNeed =
      (size_t)(2 * (N + 1) + 256 + E) * sizeof(int) + (size_t)E * 8;
  const size_t fullNeed =
      csrNeed + (size_t)N * DIM * sizeof(short) + 128 * 128 * sizeof(short);

  const int eBlocks = (E + 255) / 256;
  const int nBlocks = (N + 255) / 256;
  const int n1Blocks = (N + 256) / 256;

  if (ws_size >= csrNeed && nBlocks <= 256) {
    int* counts = (int*)d_ws;
    int* offsets = counts + (N + 1);
    int* blockSums = offsets + (N + 1);
    int* rank = blockSums + 256;
    int2* emeta = (int2*)(rank + E);
    short* xb = (short*)(emeta + E);
    short* Wb = xb + (size_t)N * DIM;

    hipMemsetAsync(counts, 0, (size_t)(N + 1) * sizeof(int), stream);

    if (ws_size >= fullNeed) {
      const int total4 = N * DIM / 4;
      const int cvtXBlocks = (total4 + 255) / 256;
      const int prepBlocks = eBlocks + cvtXBlocks + 16;
      hipLaunchKernelGGL(prep, dim3(prepBlocks), dim3(256), 0, stream, col, counts, rank, x, xb,
                         W, Wb, E, total4, eBlocks, cvtXBlocks);
      hipLaunchKernelGGL(scan_blocks, dim3(nBlocks), dim3(256), 0, stream, counts, offsets,
                         blockSums, N);
      hipLaunchKernelGGL(scan_off, dim3(n1Blocks), dim3(256), 0, stream, offsets, blockSums, N, E,
                         nBlocks);
      hipLaunchKernelGGL(fill_edges, dim3(eBlocks), dim3(256), 0, stream, row, col, nrm, offsets,
                         rank, emeta, E);
      const int t16 = (N + 15) / 16;
      hipLaunchKernelGGL(gather_gemm, dim3(t16), dim3(256), 0, stream, (const unsigned*)xb, x0,
                         offsets, emeta, Wb, out, N);
    } else {
      hipLaunchKernelGGL(count_edges, dim3(eBlocks), dim3(256), 0, stream, col, counts, rank, E);
      hipLaunchKernelGGL(scan_blocks, dim3(nBlocks), dim3(256), 0, stream, counts, offsets,
                         blockSums, N);
      hipLaunchKernelGGL(scan_off, dim3(n1Blocks), dim3(256), 0, stream, offsets, blockSums, N, E,
                         nBlocks);
      hipLaunchKernelGGL(fill_edges, dim3(eBlocks), dim3(256), 0, stream, row, col, nrm, offsets,
                         rank, emeta, E);
      const int gBlocks = (N + 3) / 4;
      hipLaunchKernelGGL(gather_nodes_f32, dim3(gBlocks), dim3(256), 0, stream, x, x0, offsets,
                         emeta, out, N);
      hipLaunchKernelGGL(final_mfma, dim3((N + 63) / 64), dim3(256), 0, stream, W, out, N);
    }
  } else {
    int total4 = N * DIM / 4;
    hipLaunchKernelGGL(init_h, dim3((total4 + 255) / 256), dim3(256), 0, stream, x0, out, total4);
    long long threads = (long long)E * 32;
    hipLaunchKernelGGL(scatter_edges, dim3((int)((threads + 255) / 256)), dim3(256), 0, stream, x,
                       row, col, nrm, out, E);
    hipLaunchKernelGGL(final_mfma, dim3((N + 63) / 64), dim3(256), 0, stream, W, out, N);
  }
}